// Round 1
// baseline (155.387 us; speedup 1.0000x reference)
//
#include <hip/hip_runtime.h>

#define BATCH   8
#define VIN     4096
#define CIN     64
#define VOUTN   16384
#define SN      9
#define COUT    32
#define VT      64   // v-positions per block in kernel 2

// Kernel 1: pooled[b,u,c] = sum_{j<3} tv[e_j] * x[b, tc[e_j], c],  e_j = row_map[u,j]
// lane = channel c -> x-row gathers and pooled stores are coalesced 256B rows.
__global__ __launch_bounds__(256) void pool_kernel(
    const float* __restrict__ x, const int* __restrict__ trans_col,
    const float* __restrict__ trans_value, const int* __restrict__ row_map,
    float* __restrict__ pooled) {
  int t  = threadIdx.x;
  int c  = t & 63;
  int gu = blockIdx.x * 4 + (t >> 6);      // global (b,u) slot, 0 .. B*VOUT
  int u  = gu & (VOUTN - 1);
  int b  = gu >> 14;                       // VOUT = 2^14
  const float* xb = x + (size_t)b * VIN * CIN;
  float acc = 0.f;
#pragma unroll
  for (int j = 0; j < 3; ++j) {
    int   e  = row_map[u * 3 + j];
    int   col = trans_col[e];
    float tv  = trans_value[e];
    acc += tv * xb[col * CIN + c];
  }
  pooled[(size_t)gu * CIN + c] = acc;
}

// Kernel 2: per block: 64 v's.
//  Phase A (lane=c): dw[vl][c] = bd[c] + sum_s Wd[c,s] * pooled[b, idx[v,s], c]
//  Phase B (lane=vl, wave w -> o in [8w, 8w+8)): pw = relu(dw . Wp^T + bp)
__global__ __launch_bounds__(256) void dwpw_kernel(
    const float* __restrict__ pooled, const int* __restrict__ indices,
    const float* __restrict__ Wd, const float* __restrict__ bd,
    const float* __restrict__ Wp, const float* __restrict__ bp,
    float* __restrict__ out) {
  __shared__ float dw[VT][65];             // pad 65: phase-B column read conflict-free
  int t = threadIdx.x;
  int c = t & 63;
  int w = t >> 6;                          // wave id 0..3
  int gv0 = blockIdx.x * VT;               // base over B*VOUT
  int b   = gv0 >> 14;
  int v0  = gv0 & (VOUTN - 1);

  // per-lane depthwise weights (lane = channel)
  float wd[SN];
#pragma unroll
  for (int s = 0; s < SN; ++s) wd[s] = Wd[c * SN + s];
  float bdc = bd[c];
  const float* pb = pooled + (size_t)b * VOUTN * CIN;

#pragma unroll 4
  for (int vl = w; vl < VT; vl += 4) {
    const int* idx = indices + (v0 + vl) * SN;
    float acc = bdc;
#pragma unroll
    for (int s = 0; s < SN; ++s) {
      int u = idx[s];
      acc += wd[s] * pb[u * CIN + c];      // coalesced 256B row per (vl,s)
    }
    dw[vl][c] = acc;
  }
  __syncthreads();

  // Phase B: lane -> vl = lane id; wave-uniform o-block (readfirstlane => scalar Wp loads)
  int vl = c;
  int ob = __builtin_amdgcn_readfirstlane(w * 8);
  float acc[8];
#pragma unroll
  for (int oo = 0; oo < 8; ++oo) acc[oo] = bp[ob + oo];
#pragma unroll 8
  for (int cc = 0; cc < CIN; ++cc) {
    float d = dw[vl][cc];                  // banks (vl+cc)%32: conflict-free
#pragma unroll
    for (int oo = 0; oo < 8; ++oo)
      acc[oo] += d * Wp[(ob + oo) * CIN + cc];   // scalar (wave-uniform)
  }
  float* op = out + (size_t)(gv0 + vl) * COUT + ob;
  float4 r0 = make_float4(fmaxf(acc[0], 0.f), fmaxf(acc[1], 0.f),
                          fmaxf(acc[2], 0.f), fmaxf(acc[3], 0.f));
  float4 r1 = make_float4(fmaxf(acc[4], 0.f), fmaxf(acc[5], 0.f),
                          fmaxf(acc[6], 0.f), fmaxf(acc[7], 0.f));
  *(float4*)op = r0;
  *(float4*)(op + 4) = r1;
}

extern "C" void kernel_launch(void* const* d_in, const int* in_sizes, int n_in,
                              void* d_out, int out_size, void* d_ws, size_t ws_size,
                              hipStream_t stream) {
  const float* x    = (const float*)d_in[0];
  // d_in[1] = trans_row (unused by the reference computation)
  const int*   tc   = (const int*)d_in[2];
  const float* tv   = (const float*)d_in[3];
  const int*   rm   = (const int*)d_in[4];
  const int*   idx  = (const int*)d_in[5];
  const float* Wd   = (const float*)d_in[6];
  const float* bd   = (const float*)d_in[7];
  const float* Wp   = (const float*)d_in[8];
  const float* bp   = (const float*)d_in[9];
  float* out = (float*)d_out;
  float* pooled = (float*)d_ws;            // 8*16384*64*4 = 32 MiB

  int n_bu = BATCH * VOUTN;                // 131072
  pool_kernel<<<n_bu / 4, 256, 0, stream>>>(x, tc, tv, rm, pooled);
  dwpw_kernel<<<n_bu / VT, 256, 0, stream>>>(pooled, idx, Wd, bd, Wp, bp, out);
}

// Round 2
// 125.983 us; speedup vs baseline: 1.2334x; 1.2334x over previous
//
#include <hip/hip_runtime.h>

#define BATCH   8
#define VIN     4096
#define CIN     64
#define VOUTN   16384
#define SN      9
#define COUT    32
#define VT      64   // v-positions per dwpw block

// Kernel 1: pooled[b,u,c] = sum_{j<3} tv[e_j] * x[b, tc[e_j], c]
// XCD-pinned: batch = blockIdx & 7 (round-robin block->XCD dispatch), so each
// XCD's L2 holds exactly one batch's x (1 MiB) and pooled slice (4 MiB).
// float4 gathers: 16 lanes cover a 256B channel row.
__global__ __launch_bounds__(256) void pool_kernel(
    const float* __restrict__ x, const int* __restrict__ trans_col,
    const float* __restrict__ trans_value, const int* __restrict__ row_map,
    float* __restrict__ pooled) {
  int t  = threadIdx.x;
  int g  = t >> 4;                          // 16 u-groups per block
  int l  = t & 15;                          // lane within row, 4 channels each
  int b  = blockIdx.x & 7;                  // XCD-pinned batch
  int u  = (blockIdx.x >> 3) * 16 + g;      // 1024 chunks/batch * 16 u
  const float4* xb4 = (const float4*)(x + (size_t)b * VIN * CIN);
  float4 acc = make_float4(0.f, 0.f, 0.f, 0.f);
#pragma unroll
  for (int j = 0; j < 3; ++j) {
    int   e   = row_map[u * 3 + j];         // 16 lanes same addr -> broadcast
    int   col = trans_col[e];
    float tv  = trans_value[e];
    float4 p  = xb4[col * 16 + l];
    acc.x += tv * p.x; acc.y += tv * p.y; acc.z += tv * p.z; acc.w += tv * p.w;
  }
  float4* pp = (float4*)(pooled + (size_t)((b << 14) + u) * CIN);
  pp[l] = acc;
}

// Kernel 2: 64 v's per block, XCD-pinned batch.
//  Phase A (16 lanes x 4ch float4): dw[vl][c] = bd[c] + sum_s Wd[c,s]*pooled[b,idx[v,s],c]
//  Phase B (lane=vl, wave w -> o in [8w,8w+8)): out = relu(dw . Wp^T + bp)
__global__ __launch_bounds__(256) void dwpw_kernel(
    const float* __restrict__ pooled, const int* __restrict__ indices,
    const float* __restrict__ Wd, const float* __restrict__ bd,
    const float* __restrict__ Wp, const float* __restrict__ bp,
    float* __restrict__ out) {
  __shared__ float dw[VT][65];              // pad 65: (vl+cc)%32 -> 2-way max (free)
  int t = threadIdx.x;
  int b  = blockIdx.x & 7;                  // XCD-pinned batch
  int v0 = (blockIdx.x >> 3) * VT;          // 256 chunks per batch

  // ---- Phase A ----
  int g  = t >> 4;                          // v-group 0..15
  int l  = t & 15;                          // 4-channel lane
  int c4 = l * 4;
  float4 wd4[SN];
#pragma unroll
  for (int s = 0; s < SN; ++s) {
    wd4[s].x = Wd[(c4 + 0) * SN + s];
    wd4[s].y = Wd[(c4 + 1) * SN + s];
    wd4[s].z = Wd[(c4 + 2) * SN + s];
    wd4[s].w = Wd[(c4 + 3) * SN + s];
  }
  float4 bd4 = *(const float4*)(bd + c4);
  const float4* pb4 = (const float4*)(pooled + (size_t)(b << 14) * CIN);

#pragma unroll
  for (int vi = 0; vi < 4; ++vi) {
    int vl = g + vi * 16;
    const int* idx = indices + (v0 + vl) * SN;
    float4 acc = bd4;
#pragma unroll
    for (int s = 0; s < SN; ++s) {
      int u = idx[s];                       // broadcast within 16-lane group
      float4 p = pb4[u * 16 + l];           // L2-resident gather (XCD-pinned)
      acc.x += wd4[s].x * p.x; acc.y += wd4[s].y * p.y;
      acc.z += wd4[s].z * p.z; acc.w += wd4[s].w * p.w;
    }
    dw[vl][c4 + 0] = acc.x; dw[vl][c4 + 1] = acc.y;
    dw[vl][c4 + 2] = acc.z; dw[vl][c4 + 3] = acc.w;
  }
  __syncthreads();

  // ---- Phase B ----
  int vl = t & 63;
  int w  = t >> 6;
  int ob = __builtin_amdgcn_readfirstlane(w * 8);   // wave-uniform o-block
  float acc[8];
#pragma unroll
  for (int oo = 0; oo < 8; ++oo) acc[oo] = bp[ob + oo];
#pragma unroll 8
  for (int cc = 0; cc < CIN; ++cc) {
    float d = dw[vl][cc];                   // bank (vl+cc)%32: 2-way, free
#pragma unroll
    for (int oo = 0; oo < 8; ++oo)
      acc[oo] += d * Wp[(ob + oo) * CIN + cc];      // scalar (wave-uniform)
  }
  float* op = out + (size_t)((b << 14) + v0 + vl) * COUT + ob;
  float4 r0 = make_float4(fmaxf(acc[0], 0.f), fmaxf(acc[1], 0.f),
                          fmaxf(acc[2], 0.f), fmaxf(acc[3], 0.f));
  float4 r1 = make_float4(fmaxf(acc[4], 0.f), fmaxf(acc[5], 0.f),
                          fmaxf(acc[6], 0.f), fmaxf(acc[7], 0.f));
  *(float4*)op = r0;
  *(float4*)(op + 4) = r1;
}

extern "C" void kernel_launch(void* const* d_in, const int* in_sizes, int n_in,
                              void* d_out, int out_size, void* d_ws, size_t ws_size,
                              hipStream_t stream) {
  const float* x    = (const float*)d_in[0];
  const int*   tc   = (const int*)d_in[2];
  const float* tv   = (const float*)d_in[3];
  const int*   rm   = (const int*)d_in[4];
  const int*   idx  = (const int*)d_in[5];
  const float* Wd   = (const float*)d_in[6];
  const float* bd   = (const float*)d_in[7];
  const float* Wp   = (const float*)d_in[8];
  const float* bp   = (const float*)d_in[9];
  float* out = (float*)d_out;
  float* pooled = (float*)d_ws;             // 32 MiB

  // pool: 8192 blocks = 8 batches * 1024 chunks (16 u each), batch = blk & 7
  pool_kernel<<<BATCH * (VOUTN / 16), 256, 0, stream>>>(x, tc, tv, rm, pooled);
  // dwpw: 2048 blocks = 8 batches * 256 chunks (64 v each), batch = blk & 7
  dwpw_kernel<<<BATCH * (VOUTN / VT), 256, 0, stream>>>(pooled, idx, Wd, bd, Wp, bp, out);
}

// Round 5
// 115.418 us; speedup vs baseline: 1.3463x; 1.0915x over previous
//
#include <hip/hip_runtime.h>

#define BATCH   8
#define VIN     4096
#define CIN     64
#define VOUTN   16384
#define SN      9
#define COUT    32
#define VT      64   // v-positions per dwpw block
#define UPB     16   // u-positions per pool block

// bf16 <-> f32 (RNE) via HIP bit intrinsics
__device__ __forceinline__ unsigned short f2bf(float f) {
  unsigned u = __float_as_uint(f);
  u += 0x7FFFu + ((u >> 16) & 1u);
  return (unsigned short)(u >> 16);
}
__device__ __forceinline__ float bf2f(unsigned short h) {
  return __uint_as_float((unsigned)h << 16);
}

// Kernel 1: pooled[b,u,c] = sum_{j<3} tv[e_j] * x[b, tc[e_j], c]  -> bf16
// XCD-pinned: batch = blockIdx & 7. Edge metadata staged in LDS (coalesced).
__global__ __launch_bounds__(256) void pool_kernel(
    const float* __restrict__ x, const int* __restrict__ trans_col,
    const float* __restrict__ trans_value, const int* __restrict__ row_map,
    unsigned short* __restrict__ pooled) {
  __shared__ int   scol[UPB * 3];
  __shared__ float sval[UPB * 3];
  int t  = threadIdx.x;
  int b  = blockIdx.x & 7;                  // XCD-pinned batch
  int u0 = (blockIdx.x >> 3) * UPB;
  if (t < UPB * 3) {
    int e   = row_map[u0 * 3 + t];          // contiguous
    scol[t] = trans_col[e];
    sval[t] = trans_value[e];
  }
  __syncthreads();
  int g = t >> 4, l = t & 15;               // 16 u-groups x 16 lanes (float4 = 256B row)
  const float4* xb4 = (const float4*)(x + (size_t)b * VIN * CIN);
  float4 acc = make_float4(0.f, 0.f, 0.f, 0.f);
#pragma unroll
  for (int j = 0; j < 3; ++j) {
    int   col = scol[g * 3 + j];            // LDS broadcast
    float tv  = sval[g * 3 + j];
    float4 p  = xb4[col * 16 + l];          // L2-resident (1 MiB x-slice per XCD)
    acc.x += tv * p.x; acc.y += tv * p.y; acc.z += tv * p.z; acc.w += tv * p.w;
  }
  ushort4 h;
  h.x = f2bf(acc.x); h.y = f2bf(acc.y); h.z = f2bf(acc.z); h.w = f2bf(acc.w);
  ((ushort4*)(pooled + (size_t)((b << 14) + u0 + g) * CIN))[l] = h;  // 128B row
}

// Kernel 2: 64 v's per block, XCD-pinned batch.
//  Phase A (16 lanes x 4ch): dw[vl][c] = bd[c] + sum_s Wd[c,s]*pooled_bf16[b,idx[v,s],c]
//  Phase B (lane=vl, wave w -> o in [8w,8w+8)): out = relu(dw . Wp^T + bp)
__global__ __launch_bounds__(256) void dwpw_kernel(
    const unsigned short* __restrict__ pooled, const int* __restrict__ indices,
    const float* __restrict__ Wd, const float* __restrict__ bd,
    const float* __restrict__ Wp, const float* __restrict__ bp,
    float* __restrict__ out) {
  __shared__ float dw[VT][65];              // pad 65: phase-B reads conflict-free
  __shared__ int   sidx[VT * SN];           // this block's 576 gather indices
  __shared__ float swdT[SN * CIN];          // Wd transposed [s][c] for float4 reads
  int t  = threadIdx.x;
  int b  = blockIdx.x & 7;                  // XCD-pinned batch
  int v0 = (blockIdx.x >> 3) * VT;

  for (int i = t; i < VT * SN; i += 256) {  // 576 coalesced loads each
    sidx[i] = indices[v0 * SN + i];
    int c = i / SN, s = i - c * SN;         // Wd flat idx i = c*SN + s
    swdT[s * CIN + c] = Wd[i];
  }
  __syncthreads();

  // ---- Phase A ----
  int g = t >> 4, l = t & 15, c4 = l * 4;
  float4 wd4[SN];
#pragma unroll
  for (int s = 0; s < SN; ++s) wd4[s] = *(const float4*)&swdT[s * CIN + c4];
  float4 bd4 = *(const float4*)(bd + c4);
  const ushort4* pb4 = (const ushort4*)(pooled + (size_t)(b << 14) * CIN);

#pragma unroll
  for (int vi = 0; vi < 4; ++vi) {
    int vl = g + vi * 16;
    float4 acc = bd4;
#pragma unroll
    for (int s = 0; s < SN; ++s) {
      int u = sidx[vl * SN + s];            // LDS broadcast within 16-lane group
      ushort4 h = pb4[u * 16 + l];          // 128B bf16 row gather, L2-resident
      acc.x += wd4[s].x * bf2f(h.x);
      acc.y += wd4[s].y * bf2f(h.y);
      acc.z += wd4[s].z * bf2f(h.z);
      acc.w += wd4[s].w * bf2f(h.w);
    }
    dw[vl][c4 + 0] = acc.x; dw[vl][c4 + 1] = acc.y;
    dw[vl][c4 + 2] = acc.z; dw[vl][c4 + 3] = acc.w;
  }
  __syncthreads();

  // ---- Phase B ----
  int vl = t & 63;
  int w  = t >> 6;
  int ob = __builtin_amdgcn_readfirstlane(w * 8);   // wave-uniform o-block
  float acc[8];
#pragma unroll
  for (int oo = 0; oo < 8; ++oo) acc[oo] = bp[ob + oo];
#pragma unroll 8
  for (int cc = 0; cc < CIN; ++cc) {
    float d = dw[vl][cc];                   // bank (vl+cc)%32: 2-way, free
#pragma unroll
    for (int oo = 0; oo < 8; ++oo)
      acc[oo] += d * Wp[(ob + oo) * CIN + cc];      // scalar (wave-uniform)
  }
  float* op = out + (size_t)((b << 14) + v0 + vl) * COUT + ob;
  float4 r0 = make_float4(fmaxf(acc[0], 0.f), fmaxf(acc[1], 0.f),
                          fmaxf(acc[2], 0.f), fmaxf(acc[3], 0.f));
  float4 r1 = make_float4(fmaxf(acc[4], 0.f), fmaxf(acc[5], 0.f),
                          fmaxf(acc[6], 0.f), fmaxf(acc[7], 0.f));
  *(float4*)op = r0;
  *(float4*)(op + 4) = r1;
}

extern "C" void kernel_launch(void* const* d_in, const int* in_sizes, int n_in,
                              void* d_out, int out_size, void* d_ws, size_t ws_size,
                              hipStream_t stream) {
  const float* x    = (const float*)d_in[0];
  const int*   tc   = (const int*)d_in[2];
  const float* tv   = (const float*)d_in[3];
  const int*   rm   = (const int*)d_in[4];
  const int*   idx  = (const int*)d_in[5];
  const float* Wd   = (const float*)d_in[6];
  const float* bd   = (const float*)d_in[7];
  const float* Wp   = (const float*)d_in[8];
  const float* bp   = (const float*)d_in[9];
  float* out = (float*)d_out;
  unsigned short* pooled = (unsigned short*)d_ws;   // 16 MiB bf16

  pool_kernel<<<BATCH * (VOUTN / UPB), 256, 0, stream>>>(x, tc, tv, rm, pooled);
  dwpw_kernel<<<BATCH * (VOUTN / VT), 256, 0, stream>>>(pooled, idx, Wd, bd, Wp, bp, out);
}